// Round 9
// baseline (152.126 us; speedup 1.0000x reference)
//
#include <hip/hip_runtime.h>

#define N_TOK 128
#define DIM   64
#define LN_EPS 1e-5f
#define SLOPE  0.01f

typedef float f32x4 __attribute__((ext_vector_type(4)));

__device__ __forceinline__ float wave_reduce_sum(float v) {
#pragma unroll
    for (int off = 32; off >= 1; off >>= 1) v += __shfl_xor(v, off, 64);
    return v;
}
__device__ __forceinline__ float wave_reduce_max(float v) {
#pragma unroll
    for (int off = 32; off >= 1; off >>= 1) v = fmaxf(v, __shfl_xor(v, off, 64));
    return v;
}

// DPP add step: v += dpp_perm(v). bound_ctrl=true -> out-of-row lanes add 0.
template<int CTRL>
__device__ __forceinline__ float dpp_add(float v) {
    int p = __builtin_amdgcn_update_dpp(0, __float_as_int(v), CTRL, 0xF, 0xF, true);
    return v + __int_as_float(p);
}
// Sum across each 16-lane row (VALU pipe only). Lanes 12..15 hold the total.
__device__ __forceinline__ float row16_sum(float v) {
    v = dpp_add<0xB1>(v);    // quad_perm [1,0,3,2] : + lane^1
    v = dpp_add<0x4E>(v);    // quad_perm [2,3,0,1] : + lane^2
    v = dpp_add<0x114>(v);   // row_shr:4
    v = dpp_add<0x118>(v);   // row_shr:8
    return v;
}
__device__ __forceinline__ float dot4(f32x4 a, f32x4 b) {
    return a[0]*b[0] + a[1]*b[1] + a[2]*b[2] + a[3]*b[3];
}

// ---------------------------------------------------------------------------
// Single fused kernel: one block per (b,i). Per iteration the 16-lane group
// owning j computes t4 = e_i*e_j (streamed out as value) and DPP-reduces
// SEVEN sums: value-LN stats (s1,s2,s3) and row-LN stats of e_j
// (u1=Σe, u2=Σe², uk=Σe·γ·wk, uq=Σe·γ·wq) — so q/k scores are derived
// in-block and kernel 0 / workspace vanish. Finish wave: LN algebra,
// leaky, softmax. One dispatch total.
// ---------------------------------------------------------------------------
__global__ __launch_bounds__(256) void k_all(
        const float* __restrict__ emb, const float* __restrict__ gamma,
        const float* __restrict__ beta, const float* __restrict__ attw,
        const float* __restrict__ attb, float* __restrict__ alphas,
        f32x4* __restrict__ value4) {
    __shared__ float2 s12v[N_TOK];   // (s1, s2) per j
    __shared__ float  s3a[N_TOK];    // s3 per j
    __shared__ f32x4  kst[N_TOK];    // (u1, u2, uk, uq) per j

    int b = blockIdx.x >> 7;
    int i = blockIdx.x & 127;
    int c  = threadIdx.x & 15;       // float4 chunk over d
    int jg = threadIdx.x >> 4;       // j-group 0..15

    const f32x4* E4 = (const f32x4*)emb + ((size_t)(b * N_TOK) << 4);
    f32x4 a4  = E4[(i << 4) | c];                          // e_i chunk
    f32x4 g4  = ((const f32x4*)gamma)[c];
    f32x4 wq4 = ((const f32x4*)attw)[c];
    f32x4 wk4 = ((const f32x4*)(attw + DIM))[c];
    f32x4 wv4 = ((const f32x4*)(attw + 2 * DIM))[c];
    f32x4 gw  = g4 * wv4;            // gamma*wv
    f32x4 gq  = g4 * wq4;            // gamma*wq
    f32x4 gk  = g4 * wk4;            // gamma*wk

    f32x4* vrow = value4 + ((size_t)blockIdx.x << 11);     // 2048 float4 / row

#pragma unroll
    for (int it = 0; it < 8; ++it) {
        int j = (it << 4) | jg;
        f32x4 e4 = E4[(j << 4) | c];                       // L2-hot
        f32x4 t4 = a4 * e4;
        vrow[(j << 4) | c] = t4;                           // coalesced dwordx4

        float s1 = t4[0] + t4[1] + t4[2] + t4[3];
        float s2 = dot4(t4, t4);
        float s3 = dot4(t4, gw);
        float u1 = e4[0] + e4[1] + e4[2] + e4[3];
        float u2 = dot4(e4, e4);
        float uk = dot4(e4, gk);
        float uq = dot4(e4, gq);
        s1 = row16_sum(s1);  s2 = row16_sum(s2);  s3 = row16_sum(s3);
        u1 = row16_sum(u1);  u2 = row16_sum(u2);
        uk = row16_sum(uk);  uq = row16_sum(uq);
        if (c == 15) {                                     // row leader
            s12v[j] = make_float2(s1, s2);
            s3a[j]  = s3;
            kst[j]  = (f32x4){u1, u2, uk, uq};
        }
    }
    __syncthreads();

    // Finish wave: q_i, k_j, v-score LN algebra, leaky, softmax over 128 j.
    if (threadIdx.x < 64) {
        int lane = threadIdx.x;
        float g = gamma[lane], bt = beta[lane];
        float wq = attw[lane], wk = attw[DIM + lane], wv = attw[2*DIM + lane];
        float Sgq = wave_reduce_sum(g * wq);
        float Sbq = wave_reduce_sum(bt * wq);
        float Sgk = wave_reduce_sum(g * wk);
        float Sbk = wave_reduce_sum(bt * wk);
        float Sg  = wave_reduce_sum(g * wv);
        float Sb  = wave_reduce_sum(bt * wv);

        // q_i from row-i stats (LDS broadcast read)
        f32x4 ki  = kst[i];
        float mui = ki[0] * (1.f / 64.f);
        float vri = ki[1] * (1.f / 64.f) - mui * mui;
        float qi  = rsqrtf(vri + LN_EPS) * (ki[3] - mui * Sgq) + Sbq + attb[0];

        float sc[2];
#pragma unroll
        for (int h = 0; h < 2; ++h) {
            int j = lane + h * 64;
            f32x4 kj = kst[j];
            float2 p = s12v[j];
            float s3 = s3a[j];
            // k_j
            float mu  = kj[0] * (1.f / 64.f);
            float var = kj[1] * (1.f / 64.f) - mu * mu;
            float kjs = rsqrtf(var + LN_EPS) * (kj[2] - mu * Sgk) + Sbk;
            // v-score from value-LN stats
            float muv  = p.x * (1.f / 64.f);
            float varv = p.y * (1.f / 64.f) - muv * muv;
            float vsc  = rsqrtf(varv + LN_EPS) * (s3 - muv * Sg) + Sb;
            float s = qi + kjs + vsc;
            sc[h] = s >= 0.f ? s : SLOPE * s;              // leaky relu
        }
        float m  = wave_reduce_max(fmaxf(sc[0], sc[1]));
        float e0 = __expf(sc[0] - m), e1 = __expf(sc[1] - m);
        float s  = wave_reduce_sum(e0 + e1);
        float inv = 1.f / s;
        float* arow = alphas + ((size_t)blockIdx.x << 7);
        arow[lane]      = e0 * inv;
        arow[lane + 64] = e1 * inv;
    }
}

extern "C" void kernel_launch(void* const* d_in, const int* in_sizes, int n_in,
                              void* d_out, int out_size, void* d_ws, size_t ws_size,
                              hipStream_t stream) {
    const float* emb   = (const float*)d_in[0];
    const float* gamma = (const float*)d_in[1];
    const float* beta  = (const float*)d_in[2];
    const float* attw  = (const float*)d_in[3];
    const float* attb  = (const float*)d_in[4];
    float* out = (float*)d_out;

    int B = in_sizes[0] / (N_TOK * DIM);             // 32
    int nrows = B * N_TOK;                           // 4096
    float* alphas = out;                             // B*N*N floats
    float* value  = out + (size_t)nrows * N_TOK;     // B*N*N*D floats

    k_all<<<dim3(nrows), dim3(256), 0, stream>>>(
        emb, gamma, beta, attw, attb, alphas, (f32x4*)value);
}